// Round 7
// baseline (913.559 us; speedup 1.0000x reference)
//
#include <hip/hip_runtime.h>
#include <hip/hip_cooperative_groups.h>
#include <stdint.h>

namespace cg = cooperative_groups;

typedef __attribute__((ext_vector_type(4))) float floatx4;
typedef __attribute__((ext_vector_type(8))) short shortx8;

#define LN_EPS 1e-5f

__device__ __forceinline__ unsigned short f2b(float f) {
  unsigned u = __builtin_bit_cast(unsigned, f);
  u = (u + 0x7FFFu + ((u >> 16) & 1u)) >> 16;
  return (unsigned short)u;
}
__device__ __forceinline__ float b2f(unsigned short h) {
  return __builtin_bit_cast(float, (unsigned)h << 16);
}

__device__ __forceinline__ void g2l16(const unsigned short* g, unsigned short* l) {
  __builtin_amdgcn_global_load_lds(
      (const __attribute__((address_space(1))) unsigned int*)g,
      (__attribute__((address_space(3))) unsigned int*)l, 16, 0, 0);
}

__device__ __forceinline__ float wave_sum(float v) {
#pragma unroll
  for (int o = 32; o; o >>= 1) v += __shfl_down(v, o, 64);
  return v;
}
__device__ __forceinline__ float block_sum(float v, float* s) {
  v = wave_sum(v);
  __syncthreads();
  if ((threadIdx.x & 63) == 0) s[threadIdx.x >> 6] = v;
  __syncthreads();
  return s[0] + s[1] + s[2] + s[3];
}

// ---------------- prep: cvt prev+toks to bf16, transpose W_proj -------------
__global__ __launch_bounds__(256) void k_prep(
    const float* __restrict__ prev, unsigned short* __restrict__ psb,
    const float* __restrict__ toks, unsigned short* __restrict__ tokb,
    const float* __restrict__ Wp, unsigned short* __restrict__ Wtp) {
  __shared__ float tile[32][33];
  const int blk = blockIdx.x;
  const int tid = threadIdx.x;
  if (blk < 25600) {
    const long chunk = (long)blk * 256 + tid;
    const float* src;
    unsigned short* dst;
    long i;
    if (chunk < 262144) { src = prev; dst = psb; i = chunk * 4; }
    else { src = toks; dst = tokb; i = (chunk - 262144) * 4; }
    floatx4 v = *(const floatx4*)(src + i);
    unsigned short t4[4];
#pragma unroll
    for (int j = 0; j < 4; j++) t4[j] = f2b(v[j]);
    *(uint2*)(dst + i) = *(uint2*)t4;
  } else {
    const int t = blk - 25600;  // 0..767: W_proj (768x1024) -> (1024x768)
    const int k0 = (t % 24) * 32, n0 = (t / 24) * 32;
    const int tx = tid & 31, ty = tid >> 5;
#pragma unroll
    for (int i = 0; i < 32; i += 8)
      tile[ty + i][tx] = Wp[(long)(k0 + ty + i) * 1024 + n0 + tx];
    __syncthreads();
#pragma unroll
    for (int i = 0; i < 32; i += 8)
      Wtp[(long)(n0 + ty + i) * 768 + k0 + tx] = f2b(tile[tx][ty + i]);
  }
}

// ---------------- proj: bf16 128x128 MFMA, BK=64, swizzle, hoisted addrs ----
__global__ __launch_bounds__(256) void k_proj128(
    const unsigned short* __restrict__ A, const unsigned short* __restrict__ Bt,
    const float* __restrict__ bias, unsigned short* __restrict__ C) {
  constexpr int K = 768;
  constexpr int N = 1024;
  __shared__ unsigned short As[128 * 64];
  __shared__ unsigned short Bs[128 * 64];
  const int tid = threadIdx.x;
  const int wave = tid >> 6, lane = tid & 63;
  const int id = blockIdx.x;
  const int m0 = (((id >> 6) << 3) + (id & 7)) * 128;  // XCD-aware swizzle
  const int n0 = ((id >> 3) & 7) * 128;
  const int wm = wave & 1, wn = wave >> 1;
  const int l16 = lane & 15, quad = lane >> 4;
  const int srow8 = lane >> 3;
  const int c8 = ((lane & 7) ^ srow8) * 8;

  const unsigned short* gA[4];
  const unsigned short* gB[4];
  unsigned short* lA[4];
  unsigned short* lB[4];
#pragma unroll
  for (int j = 0; j < 4; j++) {
    const int rb = wave * 32 + j * 8;
    gA[j] = A + (long)(m0 + rb + srow8) * K + c8;
    gB[j] = Bt + (long)(n0 + rb + srow8) * K + c8;
    lA[j] = &As[rb * 64];
    lB[j] = &Bs[rb * 64];
  }
  int offA[2][4], offB[2][4];
#pragma unroll
  for (int ks = 0; ks < 2; ks++)
#pragma unroll
    for (int i = 0; i < 4; i++) {
      int r = wm * 64 + i * 16 + l16;
      offA[ks][i] = r * 64 + (((ks * 4 + quad) ^ (r & 7)) * 8);
      r = wn * 64 + i * 16 + l16;
      offB[ks][i] = r * 64 + (((ks * 4 + quad) ^ (r & 7)) * 8);
    }

  floatx4 acc[4][4] = {};

  for (int k0 = 0; k0 < K; k0 += 64) {
#pragma unroll
    for (int j = 0; j < 4; j++) {
      g2l16(gA[j] + k0, lA[j]);
      g2l16(gB[j] + k0, lB[j]);
    }
    __syncthreads();
#pragma unroll
    for (int ks = 0; ks < 2; ks++) {
      shortx8 af[4], bf[4];
#pragma unroll
      for (int i = 0; i < 4; i++) af[i] = *(const shortx8*)&As[offA[ks][i]];
#pragma unroll
      for (int j = 0; j < 4; j++) bf[j] = *(const shortx8*)&Bs[offB[ks][j]];
#pragma unroll
      for (int i = 0; i < 4; i++)
#pragma unroll
        for (int j = 0; j < 4; j++)
          acc[i][j] = __builtin_amdgcn_mfma_f32_16x16x32_bf16(af[i], bf[j], acc[i][j], 0, 0, 0);
    }
    __syncthreads();
  }

#pragma unroll
  for (int i = 0; i < 4; i++)
#pragma unroll
    for (int j = 0; j < 4; j++) {
      const int rbase = m0 + wm * 64 + i * 16 + quad * 4;
      const int col = n0 + wn * 64 + j * 16 + l16;
      const float bval = bias[col];
#pragma unroll
      for (int r = 0; r < 4; r++)
        C[(long)(rbase + r) * N + col] = f2b(acc[i][j][r] + bval);
    }
}

// ---------------- 64x64 GEMM accumulator core (BK=64, swizzle, g2l16) -------
__device__ __forceinline__ void gemm64_acc(
    const unsigned short* __restrict__ Abase, int lda,
    const unsigned short* __restrict__ Bbase, int ldb, int K,
    unsigned short* As, unsigned short* Bs, floatx4 acc[2][2]) {
  const int tid = threadIdx.x;
  const int wave = tid >> 6, lane = tid & 63;
  const int wm = wave & 1, wn = wave >> 1;
  const int l16 = lane & 15, quad = lane >> 4;
  const int srow8 = lane >> 3;
  const int c8 = ((lane & 7) ^ srow8) * 8;

  const unsigned short* gA[2];
  const unsigned short* gB[2];
  unsigned short* lA[2];
  unsigned short* lB[2];
#pragma unroll
  for (int j = 0; j < 2; j++) {
    const int rb = wave * 16 + j * 8;
    gA[j] = Abase + (long)(rb + srow8) * lda + c8;
    gB[j] = Bbase + (long)(rb + srow8) * ldb + c8;
    lA[j] = &As[rb * 64];
    lB[j] = &Bs[rb * 64];
  }
  int offA[2][2], offB[2][2];
#pragma unroll
  for (int ks = 0; ks < 2; ks++)
#pragma unroll
    for (int i = 0; i < 2; i++) {
      int r = wm * 32 + i * 16 + l16;
      offA[ks][i] = r * 64 + (((ks * 4 + quad) ^ (r & 7)) * 8);
      r = wn * 32 + i * 16 + l16;
      offB[ks][i] = r * 64 + (((ks * 4 + quad) ^ (r & 7)) * 8);
    }

  for (int k0 = 0; k0 < K; k0 += 64) {
#pragma unroll
    for (int j = 0; j < 2; j++) {
      g2l16(gA[j] + k0, lA[j]);
      g2l16(gB[j] + k0, lB[j]);
    }
    __syncthreads();
#pragma unroll
    for (int ks = 0; ks < 2; ks++) {
      shortx8 af[2], bf[2];
#pragma unroll
      for (int i = 0; i < 2; i++) af[i] = *(const shortx8*)&As[offA[ks][i]];
#pragma unroll
      for (int j = 0; j < 2; j++) bf[j] = *(const shortx8*)&Bs[offB[ks][j]];
#pragma unroll
      for (int i = 0; i < 2; i++)
#pragma unroll
        for (int j = 0; j < 2; j++)
          acc[i][j] = __builtin_amdgcn_mfma_f32_16x16x32_bf16(af[i], bf[j], acc[i][j], 0, 0, 0);
    }
    __syncthreads();
  }
}

// ---------------- mega: whole post-proj tail, one cooperative launch --------
struct MegaParams {
  const unsigned short* psb;
  const unsigned short* tok;
  unsigned short* attnb;
  float* parts;
  unsigned short* conc;
  unsigned short* candA;
  float* ubuf;
  unsigned short* Wtur;
  unsigned short* Wtn;
  const float* Wu;
  const float* Wr;
  const float* Wn;
  const float* prev;
  const float* g_st;
  const float* be_st;
  const float* g_in;
  const float* be_in;
  const float* g_o;
  const float* be_o;
  const float* bu;
  const float* br;
  const float* bn;
  float* out;
};

__global__ __launch_bounds__(256, 2) void k_mega(MegaParams p) {
  __shared__ unsigned short As[4096];   // 8 KB
  __shared__ unsigned short Bs[4224];   // 8.25 KB (covers 64x66 routed staging)
  __shared__ float scr[4];
  cg::grid_group grid = cg::this_grid();
  const int blk = blockIdx.x;           // 512 blocks
  const int tid = threadIdx.x;
  const int wave = tid >> 6, lane = tid & 63;
  const int wm = wave & 1, wn = wave >> 1;
  const int l16 = lane & 15, quad = lane >> 4;

  // ===== S1: attnb = exp(psb @ tok^T / 32)  (unnormalized; LN scale-invar) ==
  {
    const int b = blk >> 5, nt = blk & 31;
    floatx4 acc[2][2] = {};
    gemm64_acc(p.psb + (long)b * 65536, 1024,
               p.tok + (long)b * 2097152 + (long)nt * 65536, 1024, 1024,
               As, Bs, acc);
#pragma unroll
    for (int i = 0; i < 2; i++)
#pragma unroll
      for (int j = 0; j < 2; j++) {
        const int rb = wm * 32 + i * 16 + quad * 4;
        const int c = nt * 64 + wn * 32 + j * 16 + l16;
#pragma unroll
        for (int r = 0; r < 4; r++)
          p.attnb[(long)b * 131072 + (long)(rb + r) * 2048 + c] =
              f2b(expf(acc[i][j][r] * 0.03125f));
      }
  }
  __threadfence();
  grid.sync();

  // ===== S2: parts = attnb @ tok (K-split x2) ===============================
  {
    const int kc = blk & 1, nt = (blk >> 1) & 15, b = blk >> 5;
    const int n0 = nt * 64;
    const long abase = (long)b * 131072 + (long)kc * 1024;
    const long tbase = ((long)b * 2048 + (long)kc * 1024) * 1024;
    const int srow = tid >> 2, skc = (tid & 3) * 8;
    const int bk = tid >> 3, bd = (tid & 7) * 8;
    floatx4 acc[2][2] = {};
    for (int k0 = 0; k0 < 1024; k0 += 32) {
      *(uint4*)&As[srow * 40 + skc] =
          *(const uint4*)(p.attnb + abase + (long)srow * 2048 + k0 + skc);
      {
        uint4 v = *(const uint4*)(p.tok + tbase + (long)(k0 + bk) * 1024 + n0 + bd);
        const unsigned* pv = (const unsigned*)&v;
        unsigned short* dst = &Bs[bk * 66 + bd];
#pragma unroll
        for (int w2 = 0; w2 < 4; w2++) *(unsigned*)(dst + w2 * 2) = pv[w2];
      }
      __syncthreads();
      shortx8 a0 = *(const shortx8*)&As[(wm * 32 + 0 + l16) * 40 + quad * 8];
      shortx8 a1 = *(const shortx8*)&As[(wm * 32 + 16 + l16) * 40 + quad * 8];
      shortx8 b0, b1;
#pragma unroll
      for (int j = 0; j < 8; j++) {
        b0[j] = *(const short*)&Bs[(quad * 8 + j) * 66 + wn * 32 + l16];
        b1[j] = *(const short*)&Bs[(quad * 8 + j) * 66 + wn * 32 + 16 + l16];
      }
      acc[0][0] = __builtin_amdgcn_mfma_f32_16x16x32_bf16(a0, b0, acc[0][0], 0, 0, 0);
      acc[0][1] = __builtin_amdgcn_mfma_f32_16x16x32_bf16(a0, b1, acc[0][1], 0, 0, 0);
      acc[1][0] = __builtin_amdgcn_mfma_f32_16x16x32_bf16(a1, b0, acc[1][0], 0, 0, 0);
      acc[1][1] = __builtin_amdgcn_mfma_f32_16x16x32_bf16(a1, b1, acc[1][1], 0, 0, 0);
      __syncthreads();
    }
#pragma unroll
    for (int i = 0; i < 2; i++)
#pragma unroll
      for (int j = 0; j < 2; j++) {
        const int rb = wm * 32 + i * 16 + quad * 4;
        const int c = n0 + wn * 32 + j * 16 + l16;
#pragma unroll
        for (int r = 0; r < 4; r++)
          p.parts[(long)kc * 1048576 + ((long)b * 64 + rb + r) * 1024 + c] =
              acc[i][j][r];
      }
  }
  __threadfence();
  grid.sync();

  // ===== S3: gate-weight transposes (12 tiles/blk) + both LayerNorms ========
  {
    float(*tile)[33] = (float(*)[33])As;  // 4224 B, fits in As
    const int tx = tid & 31, ty = tid >> 5;
    for (int t = blk; t < 6144; t += 512) {
      const int which = t >> 11;
      const int t2 = t & 2047;
      const float* in = which == 0 ? p.Wu : (which == 1 ? p.Wr : p.Wn);
      unsigned short* outw =
          which == 0 ? p.Wtur : (which == 1 ? p.Wtur + 1024 * 2048 : p.Wtn);
      const int k0 = (t2 & 63) * 32, n0 = (t2 >> 6) * 32;
      __syncthreads();
#pragma unroll
      for (int i = 0; i < 32; i += 8)
        tile[ty + i][tx] = in[(long)(k0 + ty + i) * 1024 + n0 + tx];
      __syncthreads();
#pragma unroll
      for (int i = 0; i < 32; i += 8)
        outw[(long)(n0 + ty + i) * 2048 + k0 + tx] = f2b(tile[tx][ty + i]);
    }
    // LayerNorms: 2048 virtual rows, 4 per block
    for (int vr = blk; vr < 2048; vr += 512) {
      const long r = vr & 1023;
      const bool second = vr >= 1024;
      floatx4 v;
      const float *g, *be;
      if (!second) {
        v = *(const floatx4*)(p.prev + r * 1024 + tid * 4);
        g = p.g_st; be = p.be_st;
      } else {
        v = *(const floatx4*)(p.parts + r * 1024 + tid * 4);
        v += *(const floatx4*)(p.parts + 1048576 + r * 1024 + tid * 4);
        g = p.g_in; be = p.be_in;
      }
      float s1 = v[0] + v[1] + v[2] + v[3];
      float s2 = v[0] * v[0] + v[1] * v[1] + v[2] * v[2] + v[3] * v[3];
      s1 = block_sum(s1, scr);
      s2 = block_sum(s2, scr);
      const float mean = s1 * (1.0f / 1024.0f);
      const float var = s2 * (1.0f / 1024.0f) - mean * mean;
      const float rstd = rsqrtf(var + LN_EPS);
#pragma unroll
      for (int i = 0; i < 4; i++) {
        const int d = tid * 4 + i;
        const float y = (v[i] - mean) * rstd * g[d] + be[d];
        const unsigned short h = f2b(y);
        if (!second) {
          p.conc[r * 2048 + d] = h;
        } else {
          p.conc[r * 2048 + 1024 + d] = h;
          p.candA[r * 2048 + 1024 + d] = h;
        }
      }
    }
  }
  __threadfence();
  grid.sync();

  // ===== S4: u|r gates: conc @ [Wu;Wr]^T ====================================
  {
    const int mi = blk >> 5, nt = blk & 31;
    floatx4 acc[2][2] = {};
    gemm64_acc(p.conc + (long)mi * 64 * 2048, 2048,
               p.Wtur + (long)nt * 64 * 2048, 2048, 2048, As, Bs, acc);
#pragma unroll
    for (int i = 0; i < 2; i++)
#pragma unroll
      for (int j = 0; j < 2; j++) {
        const int rb = mi * 64 + wm * 32 + i * 16 + quad * 4;
        const int c = nt * 64 + wn * 32 + j * 16 + l16;
#pragma unroll
        for (int r = 0; r < 4; r++) {
          const int row = rb + r;
          if (c < 1024) {
            const float v = acc[i][j][r] + p.bu[c];
            p.ubuf[(long)row * 1024 + c] = 1.0f / (1.0f + expf(-v));
          } else {
            const int cc = c - 1024;
            const float v = acc[i][j][r] + p.br[cc];
            const float rr = 1.0f / (1.0f + expf(-v));
            p.candA[(long)row * 2048 + cc] =
                f2b(rr * b2f(p.conc[(long)row * 2048 + cc]));
          }
        }
      }
  }
  __threadfence();
  grid.sync();

  // ===== S5: cand partials: candA @ Wn^T, K-split x2 -> parts ===============
  {
    const int mi = blk >> 5, nt = (blk >> 1) & 15, kc = blk & 1;
    floatx4 acc[2][2] = {};
    gemm64_acc(p.candA + (long)mi * 64 * 2048 + kc * 1024, 2048,
               p.Wtn + (long)nt * 64 * 2048 + kc * 1024, 2048, 1024, As, Bs, acc);
#pragma unroll
    for (int i = 0; i < 2; i++)
#pragma unroll
      for (int j = 0; j < 2; j++) {
        const int rb = mi * 64 + wm * 32 + i * 16 + quad * 4;
        const int c = nt * 64 + wn * 32 + j * 16 + l16;
#pragma unroll
        for (int r = 0; r < 4; r++)
          p.parts[(long)kc * 1048576 + (long)(rb + r) * 1024 + c] = acc[i][j][r];
      }
  }
  __threadfence();
  grid.sync();

  // ===== S6: combine + tanh + blend + final LN -> out =======================
  for (int rr = 0; rr < 2; rr++) {
    const long r = (long)blk * 2 + rr;
    const int d = tid * 4;
    floatx4 v = *(const floatx4*)(p.parts + r * 1024 + d);
    v += *(const floatx4*)(p.parts + 1048576 + r * 1024 + d);
    floatx4 nsv;
#pragma unroll
    for (int i = 0; i < 4; i++) {
      const float cand = tanhf(v[i] + p.bn[d + i]);
      const float u = p.ubuf[r * 1024 + d + i];
      const float pv = p.prev[r * 1024 + d + i];
      nsv[i] = (1.0f - u) * pv + u * cand;
    }
    float s1 = nsv[0] + nsv[1] + nsv[2] + nsv[3];
    float s2 = nsv[0] * nsv[0] + nsv[1] * nsv[1] + nsv[2] * nsv[2] + nsv[3] * nsv[3];
    s1 = block_sum(s1, scr);
    s2 = block_sum(s2, scr);
    const float mean = s1 * (1.0f / 1024.0f);
    const float var = s2 * (1.0f / 1024.0f) - mean * mean;
    const float rstd = rsqrtf(var + LN_EPS);
    floatx4 o;
#pragma unroll
    for (int i = 0; i < 4; i++)
      o[i] = (nsv[i] - mean) * rstd * p.g_o[d + i] + p.be_o[d + i];
    *(floatx4*)(p.out + r * 1024 + d) = o;
  }
}

// ---------------------------------------------------------------------------
extern "C" void kernel_launch(void* const* d_in, const int* in_sizes, int n_in,
                              void* d_out, int out_size, void* d_ws, size_t ws_size,
                              hipStream_t stream) {
  (void)in_sizes; (void)n_in; (void)out_size; (void)ws_size;
  const float* prev  = (const float*)d_in[0];
  const float* toks  = (const float*)d_in[1];
  const float* Wp    = (const float*)d_in[2];
  const float* bp    = (const float*)d_in[3];
  const float* g_st  = (const float*)d_in[4];
  const float* be_st = (const float*)d_in[5];
  const float* g_in  = (const float*)d_in[6];
  const float* be_in = (const float*)d_in[7];
  const float* g_o   = (const float*)d_in[8];
  const float* be_o  = (const float*)d_in[9];
  const float* Wu    = (const float*)d_in[10];
  const float* bu    = (const float*)d_in[11];
  const float* Wr    = (const float*)d_in[12];
  const float* br    = (const float*)d_in[13];
  const float* Wn    = (const float*)d_in[14];
  const float* bn    = (const float*)d_in[15];
  float* out = (float*)d_out;

  // ---- workspace (~118 MB). tokb (dead after proj) aliases region U, whose
  // contents (incl. Wtur/Wtn, written in mega S3) are only live post-proj.
  char* ws = (char*)d_ws;
  unsigned short* tok   = (unsigned short*)ws; ws += 67108864;   // 32768x1024 bf16
  unsigned short* Wtp   = (unsigned short*)ws; ws += 1572864;    // 1024x768 bf16
  unsigned short* psb   = (unsigned short*)ws; ws += 2097152;    // 1024x1024 bf16
  char* U = ws;
  unsigned short* tokb  = (unsigned short*)U;                    // 32768x768 bf16 (50.3MB)
  char* u = U;
  unsigned short* attnb = (unsigned short*)u; u += 4194304;      // 16x64x2048 bf16
  float*          parts = (float*)u;          u += 8388608;      // 2x 1024x1024 f32
  unsigned short* conc  = (unsigned short*)u; u += 4194304;      // 1024x2048 bf16
  unsigned short* candA = (unsigned short*)u; u += 4194304;      // 1024x2048 bf16
  float*          ubuf  = (float*)u;          u += 4194304;      // 1024x1024 f32
  unsigned short* Wtur  = (unsigned short*)u; u += 8388608;      // 2048x2048 bf16
  unsigned short* Wtn   = (unsigned short*)u; u += 4194304;      // 1024x2048 bf16

  const dim3 blk(256);

  // 1. prep: cvt prev+toks, transpose W_proj
  k_prep<<<dim3(26368), blk, 0, stream>>>(prev, psb, toks, tokb, Wp, Wtp);
  // 2. proj: tok = tokb @ W_proj + b_proj
  k_proj128<<<dim3(2048), blk, 0, stream>>>(tokb, Wtp, bp, tok);
  // 3. mega: scores->routed->LN+transposes->gates->cand->final LN
  MegaParams mp;
  mp.psb = psb; mp.tok = tok; mp.attnb = attnb; mp.parts = parts;
  mp.conc = conc; mp.candA = candA; mp.ubuf = ubuf;
  mp.Wtur = Wtur; mp.Wtn = Wtn; mp.Wu = Wu; mp.Wr = Wr; mp.Wn = Wn;
  mp.prev = prev;
  mp.g_st = g_st; mp.be_st = be_st; mp.g_in = g_in; mp.be_in = be_in;
  mp.g_o = g_o; mp.be_o = be_o;
  mp.bu = bu; mp.br = br; mp.bn = bn;
  mp.out = out;
  void* args[] = {&mp};
  hipLaunchCooperativeKernel((void*)k_mega, dim3(512), blk, args, 0, stream);
}